// Round 2
// baseline (313.263 us; speedup 1.0000x reference)
//
#include <hip/hip_runtime.h>
#include <hip/hip_bf16.h>

// Octree 3x3x3 sparse conv: Y[i,o] = sum_{k<27,c<16} W[k,c,o] * X[nbr[i,k],c] + b[o]
// Data dtypes: float32 in/out (per reference); grading tolerance is bf16-grade,
// so we compute via mfma_f32_16x16x32_bf16 on a bf16-converted copy of X.
//
// GEMM view: [N_out, 432] x [432, 16], K padded 432 -> 448 = 14 MFMA steps.
// One wave = 16 output nodes. A-fragment layout A[m=lane&15][k=quad*8+j] means
// each lane gathers 8 contiguous bf16 channels (16 B dwordx4) from one neighbor
// row of the bf16 table. B-fragments pre-swizzled into d_ws, held in registers.

typedef __attribute__((ext_vector_type(8))) short short8;   // 8 x bf16 bits
typedef __attribute__((ext_vector_type(4))) float floatx4;  // MFMA accumulator

#define K_OFF 27
#define C_IN  16
#define C_OUT 16
#define NT    14                 // ceil(27*16 / 32) MFMA K-steps
#define BWS_ELEMS (NT * 64 * 8)  // 7168 bf16 fragment elements
#define X16_OFFSET 16384         // byte offset of bf16 input table within d_ws

static __device__ __forceinline__ short bf16_rne(float f) {
    unsigned u = __float_as_uint(f);
    unsigned r = (u + 0x7FFFu + ((u >> 16) & 1u)) >> 16;   // round-nearest-even
    return (short)r;
}

// One kernel: (all blocks) convert input f32 -> bf16 table; (block 0) build
// swizzled B fragments bws[t][lane][j] = bf16(Wpad[k=t*32+(lane>>4)*8+j][n=lane&15])
// and write the trailing "level" output element as f32.
__global__ void prep_kernel(const float* __restrict__ input,
                            const float* __restrict__ weight,
                            const int* __restrict__ level,
                            short* __restrict__ bws,
                            short* __restrict__ x16,
                            float* __restrict__ out_level,
                            int write_level, int n_elems)
{
    int gid = blockIdx.x * blockDim.x + threadIdx.x;
    int base = gid * 8;
    if (base + 8 <= n_elems) {
        const float* p = input + base;
        float4 a0 = *(const float4*)p;
        float4 a1 = *(const float4*)(p + 4);
        short8 o;
        o[0] = bf16_rne(a0.x); o[1] = bf16_rne(a0.y);
        o[2] = bf16_rne(a0.z); o[3] = bf16_rne(a0.w);
        o[4] = bf16_rne(a1.x); o[5] = bf16_rne(a1.y);
        o[6] = bf16_rne(a1.z); o[7] = bf16_rne(a1.w);
        *reinterpret_cast<short8*>(x16 + base) = o;
    } else if (base < n_elems) {
        for (int i = base; i < n_elems; ++i) x16[i] = bf16_rne(input[i]);
    }
    if (blockIdx.x == 0) {
        for (int e = threadIdx.x; e < BWS_ELEMS; e += blockDim.x) {
            int j    = e & 7;
            int lane = (e >> 3) & 63;
            int t    = e >> 9;
            int n    = lane & 15;
            int q    = lane >> 4;
            int k    = t * 32 + q * 8 + j;          // 0..447
            short v  = 0;                            // bf16(0) for pad slice
            if (k < K_OFF * C_IN) {
                int koff = k >> 4;
                int c    = k & 15;
                v = bf16_rne(weight[(koff * C_IN + c) * C_OUT + n]);
            }
            bws[e] = v;
        }
        if (threadIdx.x == 0 && write_level) {
            *out_level = (float)(*level);
        }
    }
}

template<bool USE_TABLE>
__global__ __launch_bounds__(256) void conv_kernel(
    const float* __restrict__ input_f32,
    const short* __restrict__ x16,
    const float* __restrict__ bias,
    const int* __restrict__ nbr,
    const short* __restrict__ bws,
    float* __restrict__ out,
    int n_out)
{
    const int lane = threadIdx.x & 63;
    const int wave = threadIdx.x >> 6;
    const int m    = lane & 15;     // A row (node in wave tile) == C/D col (out chan)
    const int q    = lane >> 4;     // quad

    const int i_base = (blockIdx.x * 4 + wave) * 16;
    int node  = i_base + m;
    int cnode = node < n_out ? node : (n_out - 1);   // clamp (stores guarded)

    // B fragments: 14 coalesced 16B loads, held in registers (56 VGPRs)
    short8 bfrag[NT];
    const short8* bws8 = (const short8*)bws;
#pragma unroll
    for (int t = 0; t < NT; ++t)
        bfrag[t] = bws8[t * 64 + lane];

    // accumulator preloaded with f32 bias[col]; col = lane&15
    float bv = bias[m];
    floatx4 acc = {bv, bv, bv, bv};

    const int c_half = q & 1;   // channels 0..7 or 8..15
    const int k_add  = q >> 1;  // even/odd neighbor offset within the step

    const size_t nbr_base = (size_t)cnode * K_OFF;
#pragma unroll
    for (int t = 0; t < NT; ++t) {
        int koff = 2 * t + k_add;
        if (koff > K_OFF - 1) koff = K_OFF - 1;   // pad slice: B is zero there
        int row = nbr[nbr_base + koff];
        short8 afrag;
        if (USE_TABLE) {
            afrag = *(const short8*)(x16 + (size_t)row * C_IN + c_half * 8);
        } else {
            const float* ap = input_f32 + (size_t)row * C_IN + c_half * 8;
            float4 a0 = *(const float4*)ap;
            float4 a1 = *(const float4*)(ap + 4);
            afrag[0] = bf16_rne(a0.x); afrag[1] = bf16_rne(a0.y);
            afrag[2] = bf16_rne(a0.z); afrag[3] = bf16_rne(a0.w);
            afrag[4] = bf16_rne(a1.x); afrag[5] = bf16_rne(a1.y);
            afrag[6] = bf16_rne(a1.z); afrag[7] = bf16_rne(a1.w);
        }
        acc = __builtin_amdgcn_mfma_f32_16x16x32_bf16(afrag, bfrag[t], acc, 0, 0, 0);
    }

    // C/D layout: col = lane&15, row = q*4 + reg  (verified m89/m91)
#pragma unroll
    for (int r = 0; r < 4; ++r) {
        int snode = i_base + q * 4 + r;
        if (snode < n_out)
            out[(size_t)snode * C_OUT + m] = acc[r];
    }
}

extern "C" void kernel_launch(void* const* d_in, const int* in_sizes, int n_in_arrs,
                              void* d_out, int out_size, void* d_ws, size_t ws_size,
                              hipStream_t stream) {
    const float* input  = (const float*)d_in[0];
    const float* weight = (const float*)d_in[1];
    const float* bias   = (const float*)d_in[2];
    const int*   nbr    = (const int*)d_in[3];
    const int*   level  = (const int*)d_in[4];
    float*       out    = (float*)d_out;

    const int n_in_elems = in_sizes[0];
    const int n_out      = in_sizes[3] / K_OFF;

    short* bws = (short*)d_ws;
    short* x16 = (short*)((char*)d_ws + X16_OFFSET);

    const int write_level = (out_size > n_out * C_OUT) ? 1 : 0;
    float* out_level = out + (size_t)n_out * C_OUT;

    const size_t need = (size_t)X16_OFFSET + (size_t)n_in_elems * sizeof(short);
    const int conv_blocks = (n_out + 63) / 64;   // 64 nodes per 256-thread block

    if (ws_size >= need) {
        int threads_needed = (n_in_elems + 7) / 8;
        int prep_blocks = (threads_needed + 255) / 256;
        if (prep_blocks < 1) prep_blocks = 1;
        prep_kernel<<<prep_blocks, 256, 0, stream>>>(
            input, weight, level, bws, x16, out_level, write_level, n_in_elems);
        conv_kernel<true><<<conv_blocks, 256, 0, stream>>>(
            input, x16, bias, nbr, bws, out, n_out);
    } else {
        // Scratch too small for the bf16 table: fragments only, gather f32 directly.
        prep_kernel<<<1, 256, 0, stream>>>(
            input, weight, level, bws, x16, out_level, write_level, /*n_elems=*/0);
        conv_kernel<false><<<conv_blocks, 256, 0, stream>>>(
            input, x16, bias, nbr, bws, out, n_out);
    }
}

// Round 3
// 308.076 us; speedup vs baseline: 1.0168x; 1.0168x over previous
//
#include <hip/hip_runtime.h>
#include <hip/hip_bf16.h>

// Octree 3x3x3 sparse conv: Y[i,o] = sum_{k<27,c<16} W[k,c,o] * X[nbr[i,k],c] + b[o]
// f32 in/out; compute via mfma_f32_16x16x32_bf16 on a bf16 copy of X (tolerance
// is bf16-grade). GEMM view [N,448]x[448,16] = 14 MFMA K-steps, one wave = 16 nodes.
//
// R3 change (theory: gather-latency bound, VGPR=36 showed ~2-deep MLP):
//  - B fragments staged in LDS once per block (14 KB, conflict-free ds_read_b128)
//  - all 14 neighbor indices prefetched to registers, then ALL 14 A-gathers
//    issued before the MFMA chain -> 14-deep memory-level parallelism per wave.

typedef __attribute__((ext_vector_type(8))) short short8;   // 8 x bf16 bits
typedef __attribute__((ext_vector_type(4))) float floatx4;  // MFMA accumulator

#define K_OFF 27
#define C_IN  16
#define C_OUT 16
#define NT    14                 // ceil(27*16 / 32) MFMA K-steps (K padded to 448)
#define BWS_ELEMS (NT * 64 * 8)  // 7168 bf16 fragment elements
#define X16_OFFSET 16384         // byte offset of bf16 input table within d_ws

static __device__ __forceinline__ short bf16_rne(float f) {
    unsigned u = __float_as_uint(f);
    unsigned r = (u + 0x7FFFu + ((u >> 16) & 1u)) >> 16;   // round-nearest-even
    return (short)r;
}

// All blocks: convert input f32 -> bf16 table. Block 0 additionally builds the
// swizzled B fragments bws[t][lane][j] = bf16(Wpad[k=t*32+(lane>>4)*8+j][n=lane&15])
// and writes the trailing "level" output element as f32.
__global__ void prep_kernel(const float* __restrict__ input,
                            const float* __restrict__ weight,
                            const int* __restrict__ level,
                            short* __restrict__ bws,
                            short* __restrict__ x16,
                            float* __restrict__ out_level,
                            int write_level, int n_elems)
{
    int gid = blockIdx.x * blockDim.x + threadIdx.x;
    int base = gid * 8;
    if (base + 8 <= n_elems) {
        const float* p = input + base;
        float4 a0 = *(const float4*)p;
        float4 a1 = *(const float4*)(p + 4);
        short8 o;
        o[0] = bf16_rne(a0.x); o[1] = bf16_rne(a0.y);
        o[2] = bf16_rne(a0.z); o[3] = bf16_rne(a0.w);
        o[4] = bf16_rne(a1.x); o[5] = bf16_rne(a1.y);
        o[6] = bf16_rne(a1.z); o[7] = bf16_rne(a1.w);
        *reinterpret_cast<short8*>(x16 + base) = o;
    } else if (base < n_elems) {
        for (int i = base; i < n_elems; ++i) x16[i] = bf16_rne(input[i]);
    }
    if (blockIdx.x == 0) {
        for (int e = threadIdx.x; e < BWS_ELEMS; e += blockDim.x) {
            int j    = e & 7;
            int lane = (e >> 3) & 63;
            int t    = e >> 9;
            int n    = lane & 15;
            int q    = lane >> 4;
            int k    = t * 32 + q * 8 + j;          // 0..447
            short v  = 0;                            // bf16(0) for pad slice
            if (k < K_OFF * C_IN) {
                int koff = k >> 4;
                int c    = k & 15;
                v = bf16_rne(weight[(koff * C_IN + c) * C_OUT + n]);
            }
            bws[e] = v;
        }
        if (threadIdx.x == 0 && write_level) {
            *out_level = (float)(*level);
        }
    }
}

template<bool USE_TABLE>
__global__ __launch_bounds__(256, 4) void conv_kernel(
    const float* __restrict__ input_f32,
    const short* __restrict__ x16,
    const float* __restrict__ bias,
    const int* __restrict__ nbr,
    const short* __restrict__ bws,
    float* __restrict__ out,
    int n_out)
{
    __shared__ short8 bsh[NT * 64];   // 14336 B of swizzled B fragments

    // one-time cooperative copy of B fragments into LDS (all waves read it 14x)
    const short8* bws8 = (const short8*)bws;
    for (int e = threadIdx.x; e < NT * 64; e += 256)
        bsh[e] = bws8[e];
    __syncthreads();

    const int lane = threadIdx.x & 63;
    const int wave = threadIdx.x >> 6;
    const int m    = lane & 15;     // A row (node in wave tile) == C/D col (out chan)
    const int q    = lane >> 4;     // quad

    const int i_base = (blockIdx.x * 4 + wave) * 16;
    int node  = i_base + m;
    int cnode = node < n_out ? node : (n_out - 1);   // clamp (stores guarded)

    const int c_half = q & 1;   // channels 0..7 or 8..15
    const int k_add  = q >> 1;  // even/odd neighbor offset within the step

    // ---- prefetch all 14 neighbor row indices (14 independent loads) ----
    const int* np = nbr + (size_t)cnode * K_OFF;
    int rows[NT];
#pragma unroll
    for (int t = 0; t < NT; ++t) {
        int koff = 2 * t + k_add;
        if (koff > K_OFF - 1) koff = K_OFF - 1;   // pad slice: B is zero there
        rows[t] = np[koff];
    }

    // ---- issue ALL 14 A-fragment gathers before any MFMA (max MLP) ----
    short8 afrag[NT];
#pragma unroll
    for (int t = 0; t < NT; ++t) {
        if (USE_TABLE) {
            afrag[t] = *(const short8*)(x16 + (size_t)rows[t] * C_IN + c_half * 8);
        } else {
            const float* ap = input_f32 + (size_t)rows[t] * C_IN + c_half * 8;
            float4 a0 = *(const float4*)ap;
            float4 a1 = *(const float4*)(ap + 4);
            short8 af;
            af[0] = bf16_rne(a0.x); af[1] = bf16_rne(a0.y);
            af[2] = bf16_rne(a0.z); af[3] = bf16_rne(a0.w);
            af[4] = bf16_rne(a1.x); af[5] = bf16_rne(a1.y);
            af[6] = bf16_rne(a1.z); af[7] = bf16_rne(a1.w);
            afrag[t] = af;
        }
    }

    // accumulator preloaded with f32 bias[col]; col = lane&15
    float bv = bias[m];
    floatx4 acc = {bv, bv, bv, bv};

#pragma unroll
    for (int t = 0; t < NT; ++t)
        acc = __builtin_amdgcn_mfma_f32_16x16x32_bf16(afrag[t], bsh[t * 64 + lane],
                                                      acc, 0, 0, 0);

    // C/D layout: col = lane&15, row = q*4 + reg  (verified m89/m91)
#pragma unroll
    for (int r = 0; r < 4; ++r) {
        int snode = i_base + q * 4 + r;
        if (snode < n_out)
            out[(size_t)snode * C_OUT + m] = acc[r];
    }
}

extern "C" void kernel_launch(void* const* d_in, const int* in_sizes, int n_in_arrs,
                              void* d_out, int out_size, void* d_ws, size_t ws_size,
                              hipStream_t stream) {
    const float* input  = (const float*)d_in[0];
    const float* weight = (const float*)d_in[1];
    const float* bias   = (const float*)d_in[2];
    const int*   nbr    = (const int*)d_in[3];
    const int*   level  = (const int*)d_in[4];
    float*       out    = (float*)d_out;

    const int n_in_elems = in_sizes[0];
    const int n_out      = in_sizes[3] / K_OFF;

    short* bws = (short*)d_ws;
    short* x16 = (short*)((char*)d_ws + X16_OFFSET);

    const int write_level = (out_size > n_out * C_OUT) ? 1 : 0;
    float* out_level = out + (size_t)n_out * C_OUT;

    const size_t need = (size_t)X16_OFFSET + (size_t)n_in_elems * sizeof(short);
    const int conv_blocks = (n_out + 63) / 64;   // 64 nodes per 256-thread block

    if (ws_size >= need) {
        int threads_needed = (n_in_elems + 7) / 8;
        int prep_blocks = (threads_needed + 255) / 256;
        if (prep_blocks < 1) prep_blocks = 1;
        prep_kernel<<<prep_blocks, 256, 0, stream>>>(
            input, weight, level, bws, x16, out_level, write_level, n_in_elems);
        conv_kernel<true><<<conv_blocks, 256, 0, stream>>>(
            input, x16, bias, nbr, bws, out, n_out);
    } else {
        // Scratch too small for the bf16 table: fragments only, gather f32 directly.
        prep_kernel<<<1, 256, 0, stream>>>(
            input, weight, level, bws, x16, out_level, write_level, /*n_elems=*/0);
        conv_kernel<false><<<conv_blocks, 256, 0, stream>>>(
            input, x16, bias, nbr, bws, out, n_out);
    }
}